// Round 1
// baseline (168.102 us; speedup 1.0000x reference)
//
#include <hip/hip_runtime.h>

// ---------------------------------------------------------------------------
// VisualContrastiveLoss on MI355X
// loss = C + mean_i log(Z_i) - mean_i sim[i, lab_i],  C = 1/0.07
//   Z_i = sum_j exp(sim_ij - C)   (fixed shift: dots bounded by 1, no flash max)
//   sim = (f f^T)/0.07, f = row-normalized visual_feat
// K1: normalize rows fp32 -> bf16 (and zero Z)
// K2: fused bf16-MFMA GEMM (128x128 tile, BK=64) + exp/Z epilogue + col0/1 capture
// K3: labels + final reduction
// ---------------------------------------------------------------------------

typedef __bf16 bf16x8 __attribute__((ext_vector_type(8)));
typedef float f32x4 __attribute__((ext_vector_type(4)));

#define B_N 8192
#define D_K 512
#define INVT 14.285714285714286f
// (1/0.07) * log2(e)
#define SCALE_LOG2 20.609929155556622f

static __device__ __forceinline__ unsigned short f2bf(float f) {
  unsigned int u = __builtin_bit_cast(unsigned int, f);
  u = (u + 0x7fffu + ((u >> 16) & 1u)) >> 16;  // RNE
  return (unsigned short)u;
}

static __device__ __forceinline__ void load16_to_lds(const void* g, void* l) {
  __builtin_amdgcn_global_load_lds(
      (const __attribute__((address_space(1))) unsigned int*)g,
      (__attribute__((address_space(3))) unsigned int*)l, 16, 0, 0);
}

// ---- K1: one wave per row; normalize, convert to bf16; lane0 zeroes Z[row] --
__global__ void norm_kernel(const float* __restrict__ x,
                            unsigned short* __restrict__ fB,
                            float* __restrict__ Z) {
  const int row = blockIdx.x;
  const int lane = threadIdx.x;  // 64
  const float4* xr = (const float4*)(x + (size_t)row * D_K);
  float4 a = xr[lane];
  float4 b = xr[64 + lane];
  float s = a.x * a.x + a.y * a.y + a.z * a.z + a.w * a.w +
            b.x * b.x + b.y * b.y + b.z * b.z + b.w * b.w;
#pragma unroll
  for (int off = 1; off < 64; off <<= 1) s += __shfl_xor(s, off);
  const float inv = 1.0f / fmaxf(sqrtf(s), 1e-12f);
  ushort4 pa, pb;
  pa.x = f2bf(a.x * inv); pa.y = f2bf(a.y * inv);
  pa.z = f2bf(a.z * inv); pa.w = f2bf(a.w * inv);
  pb.x = f2bf(b.x * inv); pb.y = f2bf(b.y * inv);
  pb.z = f2bf(b.z * inv); pb.w = f2bf(b.w * inv);
  ushort4* orow = (ushort4*)(fB + (size_t)row * D_K);
  orow[lane] = pa;
  orow[64 + lane] = pb;
  if (lane == 0) Z[row] = 0.0f;  // zero accumulator (ws is poisoned each call)
}

// ---- K2: fused similarity + partial softmax-denominator ---------------------
// grid (64, 8): blockIdx.x -> 128-row tile, blockIdx.y -> 1024-col j-range.
// 4 waves in 2x2; each wave owns 64x64 C via 4x4 frags of 16x16x32 bf16 MFMA.
// A/B staged to LDS with global_load_lds(16B); 16B granules XOR-swizzled by
// (row&7) on the *global source* so ds_read_b128 frag reads are conflict-free.
__global__ __launch_bounds__(256, 2)
void sim_kernel(const unsigned short* __restrict__ fB,
                float* __restrict__ Z, float* __restrict__ T01) {
  __shared__ unsigned short ldsA[128 * 64];
  __shared__ unsigned short ldsB[128 * 64];

  const int tid = threadIdx.x;
  const int lane = tid & 63;
  const int w = tid >> 6;
  const int wm = w & 1;       // wave row strip (0/1) -> rows wm*64..
  const int wn = w >> 1;      // wave col strip (0/1) -> cols wn*64..
  const int I0 = blockIdx.x * 128;
  const int Jbase = blockIdx.y * 1024;

  // staging lane geometry: 8 rows x 8 granules(16B) per instruction
  const int srow = lane >> 3;                 // 0..7
  const int sg = (lane & 7) ^ srow;           // swizzled source granule
  const size_t sOff = (size_t)srow * D_K + sg * 8;  // elements

  // fragment-read lane geometry
  const int fr = lane & 15;   // M/N index within 16
  const int q = lane >> 4;    // quad -> k granule
  const int swz = lane & 7;   // row&7 of the frag row

  float Zp[4][4];
#pragma unroll
  for (int m = 0; m < 4; ++m)
#pragma unroll
    for (int r = 0; r < 4; ++r) Zp[m][r] = 0.0f;

  for (int jt = 0; jt < 8; ++jt) {
    const int J0 = Jbase + jt * 128;
    f32x4 acc[4][4];
#pragma unroll
    for (int m = 0; m < 4; ++m)
#pragma unroll
      for (int n = 0; n < 4; ++n) acc[m][n] = (f32x4){0.f, 0.f, 0.f, 0.f};

    for (int kk = 0; kk < 8; ++kk) {
      const int k0 = kk * 64;
      const int rbase = w * 32;
      const unsigned short* gA = fB + (size_t)(I0 + rbase) * D_K + k0 + sOff;
      const unsigned short* gB = fB + (size_t)(J0 + rbase) * D_K + k0 + sOff;
      unsigned short* lA = ldsA + rbase * 64;
      unsigned short* lB = ldsB + rbase * 64;
#pragma unroll
      for (int rr = 0; rr < 32; rr += 8) {
        load16_to_lds(gA + (size_t)rr * D_K, lA + rr * 64);
        load16_to_lds(gB + (size_t)rr * D_K, lB + rr * 64);
      }
      __syncthreads();
#pragma unroll
      for (int s = 0; s < 2; ++s) {
        const int slot = ((s * 4 + q) ^ swz) * 8;
        bf16x8 av[4], bv[4];
#pragma unroll
        for (int m = 0; m < 4; ++m)
          av[m] = *(const bf16x8*)(ldsA + (wm * 64 + m * 16 + fr) * 64 + slot);
#pragma unroll
        for (int n = 0; n < 4; ++n)
          bv[n] = *(const bf16x8*)(ldsB + (wn * 64 + n * 16 + fr) * 64 + slot);
#pragma unroll
        for (int m = 0; m < 4; ++m)
#pragma unroll
          for (int n = 0; n < 4; ++n)
            acc[m][n] = __builtin_amdgcn_mfma_f32_16x16x32_bf16(
                av[m], bv[n], acc[m][n], 0, 0, 0);
      }
      __syncthreads();
    }

    // capture sim[:,0] and sim[:,1] (cols 0,1 live in j-tile 0, wn==0, n==0)
    if (blockIdx.y == 0 && jt == 0 && wn == 0 && fr < 2) {
#pragma unroll
      for (int m = 0; m < 4; ++m)
#pragma unroll
        for (int r = 0; r < 4; ++r) {
          const int row = I0 + wm * 64 + m * 16 + q * 4 + r;
          T01[row * 2 + fr] = acc[m][0][r] * INVT;
        }
    }

    // Z partials: exp((dot-1)/T) summed over this wave's 64 cols
#pragma unroll
    for (int m = 0; m < 4; ++m)
#pragma unroll
      for (int n = 0; n < 4; ++n)
#pragma unroll
        for (int r = 0; r < 4; ++r)
          Zp[m][r] += exp2f((acc[m][n][r] - 1.0f) * SCALE_LOG2);
  }

  // reduce Zp across the 16 col-lanes (low 4 lane bits), then atomicAdd
#pragma unroll
  for (int m = 0; m < 4; ++m)
#pragma unroll
    for (int r = 0; r < 4; ++r) {
      float v = Zp[m][r];
      v += __shfl_xor(v, 1);
      v += __shfl_xor(v, 2);
      v += __shfl_xor(v, 4);
      v += __shfl_xor(v, 8);
      if (fr == 0) atomicAdd(&Z[I0 + wm * 64 + m * 16 + q * 4 + r], v);
    }
}

// ---- K3: labels + final loss reduction -------------------------------------
__global__ void finalize_kernel(const float* __restrict__ Z,
                                const float* __restrict__ T01,
                                const int* __restrict__ ids,
                                const int* __restrict__ anchor,
                                float* __restrict__ out) {
  __shared__ float red[256];
  const int t = threadIdx.x;
  const int anchor_id = ids[anchor[0]];
  const int sameLast = (ids[B_N - 1] == anchor_id);
  const int samePrev = (ids[B_N - 2] == anchor_id);
  float sum = 0.0f;
  for (int i = t; i < B_N; i += 256) {
    const int same_i = (ids[i] == anchor_id);
    const int lab = (i < B_N - 1) ? (same_i & sameLast) : (sameLast & samePrev);
    const float tt = T01[i * 2 + lab];
    sum += tt - (INVT + logf(Z[i]));
  }
  red[t] = sum;
  __syncthreads();
  for (int off = 128; off > 0; off >>= 1) {
    if (t < off) red[t] += red[t + off];
    __syncthreads();
  }
  if (t == 0) out[0] = -red[0] / (float)B_N;
}

// ---------------------------------------------------------------------------
extern "C" void kernel_launch(void* const* d_in, const int* in_sizes, int n_in,
                              void* d_out, int out_size, void* d_ws, size_t ws_size,
                              hipStream_t stream) {
  const float* x = (const float*)d_in[0];
  const int* ids = (const int*)d_in[1];
  const int* anchor = (const int*)d_in[2];
  float* out = (float*)d_out;

  unsigned short* fB = (unsigned short*)d_ws;                  // 8 MB bf16
  float* Z = (float*)((char*)d_ws + (size_t)B_N * D_K * 2);    // 32 KB
  float* T01 = Z + B_N;                                        // 64 KB

  norm_kernel<<<B_N, 64, 0, stream>>>(x, fB, Z);
  sim_kernel<<<dim3(64, 8), 256, 0, stream>>>(fB, Z, T01);
  finalize_kernel<<<1, 256, 0, stream>>>(Z, T01, ids, anchor, out);
}

// Round 2
// 138.180 us; speedup vs baseline: 1.2165x; 1.2165x over previous
//
#include <hip/hip_runtime.h>

// ---------------------------------------------------------------------------
// VisualContrastiveLoss on MI355X
// loss = C + mean_i log(Z_i) - mean_i sim[i, lab_i],  C = 1/0.07
//   Z_i = sum_j exp(sim_ij - C)   (fixed shift: dots bounded by 1)
//   sim = (f f^T)/0.07, f = row-normalized visual_feat
// R2: wave tile 64x128 (block 128x256) -> LDS-read/MFMA ratio 0.375 (was 0.5),
//     2x MFMA per barrier, bigger norm/finalize blocks.
// ---------------------------------------------------------------------------

typedef __bf16 bf16x8 __attribute__((ext_vector_type(8)));
typedef float f32x4 __attribute__((ext_vector_type(4)));

#define B_N 8192
#define D_K 512
#define INVT 14.285714285714286f
// (1/0.07) * log2(e)
#define SCALE_LOG2 20.609929155556622f

static __device__ __forceinline__ unsigned short f2bf(float f) {
  unsigned int u = __builtin_bit_cast(unsigned int, f);
  u = (u + 0x7fffu + ((u >> 16) & 1u)) >> 16;  // RNE
  return (unsigned short)u;
}

static __device__ __forceinline__ void load16_to_lds(const void* g, void* l) {
  __builtin_amdgcn_global_load_lds(
      (const __attribute__((address_space(1))) unsigned int*)g,
      (__attribute__((address_space(3))) unsigned int*)l, 16, 0, 0);
}

// ---- K1: 4 waves/block, one wave per row; normalize fp32 -> bf16 ------------
__global__ __launch_bounds__(256)
void norm_kernel(const float* __restrict__ x,
                 unsigned short* __restrict__ fB,
                 float* __restrict__ Z) {
  const int row = blockIdx.x * 4 + (threadIdx.x >> 6);
  const int lane = threadIdx.x & 63;
  const float4* xr = (const float4*)(x + (size_t)row * D_K);
  float4 a = xr[lane];
  float4 b = xr[64 + lane];
  float s = a.x * a.x + a.y * a.y + a.z * a.z + a.w * a.w +
            b.x * b.x + b.y * b.y + b.z * b.z + b.w * b.w;
#pragma unroll
  for (int off = 1; off < 64; off <<= 1) s += __shfl_xor(s, off);
  const float inv = 1.0f / fmaxf(sqrtf(s), 1e-12f);
  ushort4 pa, pb;
  pa.x = f2bf(a.x * inv); pa.y = f2bf(a.y * inv);
  pa.z = f2bf(a.z * inv); pa.w = f2bf(a.w * inv);
  pb.x = f2bf(b.x * inv); pb.y = f2bf(b.y * inv);
  pb.z = f2bf(b.z * inv); pb.w = f2bf(b.w * inv);
  ushort4* orow = (ushort4*)(fB + (size_t)row * D_K);
  orow[lane] = pa;
  orow[64 + lane] = pb;
  if (lane == 0) Z[row] = 0.0f;
}

// ---- K2: fused similarity + partial softmax-denominator ---------------------
// grid (64, 8): blockIdx.x -> 128-row tile, blockIdx.y -> 1024-col j-range
// (4 jt iterations of 256 cols). 4 waves in 2x2; each wave owns 64x128 C via
// 4x8 frags of 16x16x32 bf16 MFMA. 16B LDS granules XOR-swizzled by (row&7)
// on the global source so ds_read_b128 frag reads are conflict-free.
__global__ __launch_bounds__(256, 2)
void sim_kernel(const unsigned short* __restrict__ fB,
                float* __restrict__ Z, float* __restrict__ T01) {
  __shared__ unsigned short ldsA[128 * 64];   // 16 KB
  __shared__ unsigned short ldsB[256 * 64];   // 32 KB

  const int tid = threadIdx.x;
  const int lane = tid & 63;
  const int w = tid >> 6;
  const int wm = w & 1;       // wave row strip (0/1) -> rows wm*64..
  const int wn = w >> 1;      // wave col strip (0/1) -> cols wn*128..
  const int I0 = blockIdx.x * 128;
  const int Jbase = blockIdx.y * 1024;

  // staging lane geometry: 8 rows x 8 granules(16B) per instruction
  const int srow = lane >> 3;                 // 0..7
  const int sg = (lane & 7) ^ srow;           // swizzled source granule
  const size_t sOff = (size_t)srow * D_K + sg * 8;  // elements

  // fragment-read lane geometry
  const int fr = lane & 15;   // M/N index within 16
  const int q = lane >> 4;    // quad -> k granule
  const int swz = lane & 7;   // row&7 of the frag row

  float Zp[4][4];
#pragma unroll
  for (int m = 0; m < 4; ++m)
#pragma unroll
    for (int r = 0; r < 4; ++r) Zp[m][r] = 0.0f;

  for (int jt = 0; jt < 4; ++jt) {
    const int J0 = Jbase + jt * 256;
    f32x4 acc[4][8];
#pragma unroll
    for (int m = 0; m < 4; ++m)
#pragma unroll
      for (int n = 0; n < 8; ++n) acc[m][n] = (f32x4){0.f, 0.f, 0.f, 0.f};

    for (int kk = 0; kk < 8; ++kk) {
      const int k0 = kk * 64;
      // A: 128 rows, wave w stages rows w*32..w*32+31 (4 instrs)
      {
        const unsigned short* gA = fB + (size_t)(I0 + w * 32) * D_K + k0 + sOff;
        unsigned short* lA = ldsA + (w * 32) * 64;
#pragma unroll
        for (int rr = 0; rr < 32; rr += 8)
          load16_to_lds(gA + (size_t)rr * D_K, lA + rr * 64);
      }
      // B: 256 rows, wave w stages rows w*64..w*64+63 (8 instrs)
      {
        const unsigned short* gB = fB + (size_t)(J0 + w * 64) * D_K + k0 + sOff;
        unsigned short* lB = ldsB + (w * 64) * 64;
#pragma unroll
        for (int rr = 0; rr < 64; rr += 8)
          load16_to_lds(gB + (size_t)rr * D_K, lB + rr * 64);
      }
      __syncthreads();
#pragma unroll
      for (int s = 0; s < 2; ++s) {
        const int slot = ((s * 4 + q) ^ swz) * 8;
        bf16x8 av[4], bv[8];
#pragma unroll
        for (int m = 0; m < 4; ++m)
          av[m] = *(const bf16x8*)(ldsA + (wm * 64 + m * 16 + fr) * 64 + slot);
#pragma unroll
        for (int n = 0; n < 8; ++n)
          bv[n] = *(const bf16x8*)(ldsB + (wn * 128 + n * 16 + fr) * 64 + slot);
#pragma unroll
        for (int m = 0; m < 4; ++m)
#pragma unroll
          for (int n = 0; n < 8; ++n)
            acc[m][n] = __builtin_amdgcn_mfma_f32_16x16x32_bf16(
                av[m], bv[n], acc[m][n], 0, 0, 0);
      }
      __syncthreads();
    }

    // capture sim[:,0] and sim[:,1] (cols 0,1: j-tile 0, wn==0, n==0, fr<2)
    if (blockIdx.y == 0 && jt == 0 && wn == 0 && fr < 2) {
#pragma unroll
      for (int m = 0; m < 4; ++m)
#pragma unroll
        for (int r = 0; r < 4; ++r) {
          const int row = I0 + wm * 64 + m * 16 + q * 4 + r;
          T01[row * 2 + fr] = acc[m][0][r] * INVT;
        }
    }

    // Z partials: exp((dot-1)/T) summed over this wave's 128 cols
#pragma unroll
    for (int m = 0; m < 4; ++m)
#pragma unroll
      for (int n = 0; n < 8; ++n)
#pragma unroll
        for (int r = 0; r < 4; ++r)
          Zp[m][r] += exp2f((acc[m][n][r] - 1.0f) * SCALE_LOG2);
  }

  // reduce Zp across the 16 col-lanes (low 4 lane bits), then atomicAdd
#pragma unroll
  for (int m = 0; m < 4; ++m)
#pragma unroll
    for (int r = 0; r < 4; ++r) {
      float v = Zp[m][r];
      v += __shfl_xor(v, 1);
      v += __shfl_xor(v, 2);
      v += __shfl_xor(v, 4);
      v += __shfl_xor(v, 8);
      if (fr == 0) atomicAdd(&Z[I0 + wm * 64 + m * 16 + q * 4 + r], v);
    }
}

// ---- K3: labels + final loss reduction -------------------------------------
__global__ __launch_bounds__(1024)
void finalize_kernel(const float* __restrict__ Z,
                     const float* __restrict__ T01,
                     const int* __restrict__ ids,
                     const int* __restrict__ anchor,
                     float* __restrict__ out) {
  __shared__ float red[1024];
  const int t = threadIdx.x;
  const int anchor_id = ids[anchor[0]];
  const int sameLast = (ids[B_N - 1] == anchor_id);
  const int samePrev = (ids[B_N - 2] == anchor_id);
  float sum = 0.0f;
#pragma unroll
  for (int it = 0; it < B_N / 1024; ++it) {
    const int i = it * 1024 + t;
    const int same_i = (ids[i] == anchor_id);
    const int lab = (i < B_N - 1) ? (same_i & sameLast) : (sameLast & samePrev);
    const float tt = T01[i * 2 + lab];
    sum += tt - (INVT + logf(Z[i]));
  }
  red[t] = sum;
  __syncthreads();
  for (int off = 512; off > 0; off >>= 1) {
    if (t < off) red[t] += red[t + off];
    __syncthreads();
  }
  if (t == 0) out[0] = -red[0] / (float)B_N;
}

// ---------------------------------------------------------------------------
extern "C" void kernel_launch(void* const* d_in, const int* in_sizes, int n_in,
                              void* d_out, int out_size, void* d_ws, size_t ws_size,
                              hipStream_t stream) {
  const float* x = (const float*)d_in[0];
  const int* ids = (const int*)d_in[1];
  const int* anchor = (const int*)d_in[2];
  float* out = (float*)d_out;

  unsigned short* fB = (unsigned short*)d_ws;                  // 8 MB bf16
  float* Z = (float*)((char*)d_ws + (size_t)B_N * D_K * 2);    // 32 KB
  float* T01 = Z + B_N;                                        // 64 KB

  norm_kernel<<<B_N / 4, 256, 0, stream>>>(x, fB, Z);
  sim_kernel<<<dim3(64, 8), 256, 0, stream>>>(fB, Z, T01);
  finalize_kernel<<<1, 1024, 0, stream>>>(Z, T01, ids, anchor, out);
}